// Round 5
// baseline (249.940 us; speedup 1.0000x reference)
//
#include <hip/hip_runtime.h>
#include <math.h>

#define Dm 1024
#define Hn 16
#define HDn 64
#define Sn 1024

typedef __attribute__((ext_vector_type(8))) __bf16 bf16x8;
typedef __attribute__((ext_vector_type(4))) float floatx4;

__device__ __forceinline__ void async_ld16(void* lds, const void* g) {
    __builtin_amdgcn_global_load_lds(
        (const __attribute__((address_space(1))) void*)g,
        (__attribute__((address_space(3))) void*)lds,
        16, 0, 0);
}

// ---------------------------------------------------------------------------
// Prep kernel. grid (2048, 1, 8), 256 thr.  (round-0 version, unchanged)
// ---------------------------------------------------------------------------
struct PrepArgs {
    const float* qkv[3];
    __bf16*      qkv_o[3];
    const float* W[4];
    __bf16*      WT[4];
    float*       out_zero;
};

__global__ __launch_bounds__(256) void prep_kernel(PrepArgs a)
{
    __shared__ float sT[64][65];
    const int z = blockIdx.z, x = blockIdx.x, tid = threadIdx.x;

    if (z < 3) {
        const float* src = a.qkv[z];
        __bf16* dst = a.qkv_o[z];
        const int lin = x * 256 + tid;
        const float4 v0 = ((const float4*)src)[lin * 2];
        const float4 v1 = ((const float4*)src)[lin * 2 + 1];
        bf16x8 o;
        o[0] = (__bf16)v0.x; o[1] = (__bf16)v0.y; o[2] = (__bf16)v0.z; o[3] = (__bf16)v0.w;
        o[4] = (__bf16)v1.x; o[5] = (__bf16)v1.y; o[6] = (__bf16)v1.z; o[7] = (__bf16)v1.w;
        ((bf16x8*)dst)[lin] = o;
    } else if (z < 7) {
        if (x >= 256) return;
        const float* W = a.W[z - 3];
        __bf16* O = a.WT[z - 3];
        const int bi = (x >> 4) * 64, bj = (x & 15) * 64;
        const int colr = tid & 63, rowg = tid >> 6;
        #pragma unroll
        for (int i = 0; i < 16; ++i) {
            const int kk = i * 4 + rowg;
            sT[kk][colr] = W[(size_t)(bi + kk) * Dm + bj + colr];
        }
        __syncthreads();
        #pragma unroll
        for (int i = 0; i < 16; ++i) {
            const int rn = i * 4 + rowg;
            O[(size_t)(bj + rn) * Dm + bi + colr] = (__bf16)sT[colr][rn];
        }
    } else {
        float4* o = (float4*)a.out_zero;
        const int i = (x * 256 + tid) * 2;
        const float4 zz = make_float4(0.f, 0.f, 0.f, 0.f);
        o[i] = zz;
        o[i + 1] = zz;
    }
}

// ---------------------------------------------------------------------------
// QKV GEMM, 8-phase 256x256 schedule (T2+T3+T4+T5 port of the m201 template).
// 512 thr = 8 waves (2M x 4N), per-wave output 128x64 (8x4 frags 16x16x32).
// BK=64, K=1024 -> 16 K-tiles, 8 main iterations of 2 K-tiles / 8 phases.
// LDS 128KB: A[2buf][2half][128x64] | B[2buf][2half][128x64]; half=16KB,
// staged by 2 global_load_lds/thread. XOR swizzle (verified round-2/round-4
// family): LDS slot (row p, chunk cc) holds global k-chunk cc^(p&7).
//
// Stage/gate schedule (iteration computes K-tile T from buf0 ph0-3, T+1 from
// buf1 ph4-7; every stage targets a region whose last reader finished >=1
// barrier earlier):
//   ph0: read B(8)+A-mi01(4) of buf0; stage (T+1).A0 -> buf1.A0
//   ph1: A-mi23;               stage (T+1).A1 -> buf1.A1
//   ph2: A-mi45;               stage (T+2).B0 -> buf0.B0   (B consumed ph0)
//   ph3: A-mi67;               stage (T+2).B1 -> buf0.B1;  vmcnt(4)
//   ph4: read B'+A'-mi01 of buf1; stage (T+2).A0 -> buf0.A0 (A done ph3)
//   ph5: A'-mi23;              stage (T+2).A1 -> buf0.A1
//   ph6: A'-mi45;              stage (T+3).B0 -> buf1.B0   (B' consumed ph4)
//   ph7: A'-mi67;              stage (T+3).B1 -> buf1.B1;  vmcnt(4)
// Gate proof: at ph3's vmcnt(4) the in-flight set is <= {(T+2).B x2 halves};
// everything older — (T+1).B (prev ph6/7) and (T+1).A (ph0/1) — has landed,
// so ph4-7 reads are safe. Symmetric at ph7 for the next iteration's buf0.
// Counted vmcnt never drains to 0 in the loop (T4). Last iteration's
// (T+2)/(T+3) stage indices wrap (&15) -> harmless L2-hot junk into dead bufs.
// Each phase: {ds reads, stage, [vmcnt], barrier, lgkmcnt0+SGB (rule 18),
// setprio(1) MFMA x16 setprio(0) (T5), barrier+SGB}.
// Grid 192 blocks (16m x 4n x 3inst), bijective XCD swizzle (192%8==0).
// ---------------------------------------------------------------------------
struct GemmArgs {
    const __bf16* X[3];
    const __bf16* WT[3];
    const float*  bias[3];
    void*         out[3];
    int   layout[3];
    float esc[3];
};

__global__ __launch_bounds__(512, 2) void gemm_qkv_8ph(GemmArgs args)
{
    __shared__ __align__(16) char ldsA[65536];
    __shared__ __align__(16) char ldsB[65536];

    const int bid = blockIdx.x;
    const int wg  = (bid & 7) * 24 + (bid >> 3);     // bijective XCD swizzle
    const int z   = wg >> 6;
    const int rr_ = wg & 63;
    const int bm  = (rr_ & 15) << 8;
    const int bn  = (rr_ >> 4) << 8;

    const __bf16* __restrict__ Xb   = args.X[z];
    const __bf16* __restrict__ WTb  = args.WT[z];
    const float*  __restrict__ bias = args.bias[z];
    void* __restrict__ outp = args.out[z];
    const int layout = args.layout[z];
    const float escale = args.esc[z];

    const int tid  = threadIdx.x;
    const int lane = tid & 63, wave = tid >> 6;
    const int wm8  = wave >> 2;          // 0..1  (M wave-row)
    const int wn8  = wave & 3;           // 0..3  (N wave-col)
    const int l15  = lane & 15, quad = lane >> 4;

    floatx4 acc[8][4];
    #pragma unroll
    for (int mi = 0; mi < 8; ++mi)
        #pragma unroll
        for (int ni = 0; ni < 4; ++ni)
            acc[mi][ni] = (floatx4){0.f, 0.f, 0.f, 0.f};

    // staging: per half-tile, thread handles rows p0 and p0+64, k-chunk g0
    const int p0 = tid >> 3;
    const int g0 = (tid & 7) ^ (p0 & 7);
    const __bf16* gA = Xb  + (size_t)(bm + p0) * Dm + g0 * 8;
    const __bf16* gB = WTb + (size_t)(bn + p0) * Dm + g0 * 8;
    const int ldsw = wave * 1024;        // wave-uniform dest base offset

    auto STAGE = [&](char* arena, int buf, int half, const __bf16* gbase, int tk) {
        char* d = arena + (((buf << 1) + half) << 14) + ldsw;
        const __bf16* s = gbase + (size_t)half * 128 * Dm + tk * 64;
        async_ld16(d,        s);
        async_ld16(d + 8192, s + 64 * Dm);
    };
    auto LDA = [&](bf16x8* aq, int buf, int miBase) {
        const char* base = ldsA + (((buf << 1) + wm8) << 14);
        #pragma unroll
        for (int m = 0; m < 2; ++m) {
            const int p = (miBase + m) * 16 + l15;
            #pragma unroll
            for (int ks = 0; ks < 2; ++ks)
                aq[m * 2 + ks] = *(const bf16x8*)(base + p * 128 +
                    ((((ks << 2) | quad)) ^ (p & 7)) * 16);
        }
    };
    auto LDB = [&](bf16x8 (*bb)[2], int buf) {
        const char* base = ldsB + (((buf << 1) + (wn8 >> 1)) << 14);
        #pragma unroll
        for (int n = 0; n < 4; ++n) {
            const int p = (wn8 & 1) * 64 + n * 16 + l15;
            #pragma unroll
            for (int ks = 0; ks < 2; ++ks)
                bb[n][ks] = *(const bf16x8*)(base + p * 128 +
                    ((((ks << 2) | quad)) ^ (p & 7)) * 16);
        }
    };
    auto MF = [&](const bf16x8* aq, bf16x8 (*bb)[2], int miBase) {
        __builtin_amdgcn_s_setprio(1);
        #pragma unroll
        for (int m = 0; m < 2; ++m)
            #pragma unroll
            for (int n = 0; n < 4; ++n)
                #pragma unroll
                for (int ks = 0; ks < 2; ++ks)
                    acc[miBase + m][n] = __builtin_amdgcn_mfma_f32_16x16x32_bf16(
                        aq[m * 2 + ks], bb[n][ks], acc[miBase + m][n], 0, 0, 0);
        __builtin_amdgcn_s_setprio(0);
    };

#define PH_MID() do { __builtin_amdgcn_s_barrier(); \
    asm volatile("s_waitcnt lgkmcnt(0)" ::: "memory"); \
    __builtin_amdgcn_sched_barrier(0); } while (0)
#define PH_END() do { __builtin_amdgcn_s_barrier(); \
    __builtin_amdgcn_sched_barrier(0); } while (0)
#define VMW4()   do { asm volatile("s_waitcnt vmcnt(4)" ::: "memory"); } while (0)

    // prologue: K0 full into buf0, K1.B into buf1.B; wait K0 (vmcnt(4))
    STAGE(ldsA, 0, 0, gA, 0);  STAGE(ldsA, 0, 1, gA, 0);
    STAGE(ldsB, 0, 0, gB, 0);  STAGE(ldsB, 0, 1, gB, 0);
    STAGE(ldsB, 1, 0, gB, 1);  STAGE(ldsB, 1, 1, gB, 1);
    VMW4();
    __builtin_amdgcn_s_barrier();
    __builtin_amdgcn_sched_barrier(0);

    bf16x8 bb[4][2];
    bf16x8 aq[4];

    for (int it = 0; it < 8; ++it) {
        const int T = it << 1;
        // ---- ph0
        LDB(bb, 0); LDA(aq, 0, 0);
        STAGE(ldsA, 1, 0, gA, T + 1);
        PH_MID(); MF(aq, bb, 0); PH_END();
        // ---- ph1
        LDA(aq, 0, 2);
        STAGE(ldsA, 1, 1, gA, T + 1);
        PH_MID(); MF(aq, bb, 2); PH_END();
        // ---- ph2
        LDA(aq, 0, 4);
        STAGE(ldsB, 0, 0, gB, (T + 2) & 15);
        PH_MID(); MF(aq, bb, 4); PH_END();
        // ---- ph3
        LDA(aq, 0, 6);
        STAGE(ldsB, 0, 1, gB, (T + 2) & 15);
        VMW4();
        PH_MID(); MF(aq, bb, 6); PH_END();
        // ---- ph4
        LDB(bb, 1); LDA(aq, 1, 0);
        STAGE(ldsA, 0, 0, gA, (T + 2) & 15);
        PH_MID(); MF(aq, bb, 0); PH_END();
        // ---- ph5
        LDA(aq, 1, 2);
        STAGE(ldsA, 0, 1, gA, (T + 2) & 15);
        PH_MID(); MF(aq, bb, 2); PH_END();
        // ---- ph6
        LDA(aq, 1, 4);
        STAGE(ldsB, 1, 0, gB, (T + 3) & 15);
        PH_MID(); MF(aq, bb, 4); PH_END();
        // ---- ph7
        LDA(aq, 1, 6);
        STAGE(ldsB, 1, 1, gB, (T + 3) & 15);
        VMW4();
        PH_MID(); MF(aq, bb, 6); PH_END();
    }

#undef PH_MID
#undef PH_END
#undef VMW4

    // epilogue: bias + ReLU + escale, scatter to heads
    #pragma unroll
    for (int ni = 0; ni < 4; ++ni) {
        const int n = bn + wn8 * 64 + ni * 16 + l15;
        const float bv = bias[n];
        const int h = n >> 6, d = n & 63;
        #pragma unroll
        for (int mi = 0; mi < 8; ++mi) {
            #pragma unroll
            for (int reg = 0; reg < 4; ++reg) {
                const int m = bm + wm8 * 128 + mi * 16 + quad * 4 + reg;
                const int b = m >> 10, s = m & 1023;
                float v = fmaxf(acc[mi][ni][reg] + bv, 0.0f) * escale;
                if (layout == 0)
                    ((__bf16*)outp)[((size_t)(b * Hn + h) * 1024 + s) * 64 + d] = (__bf16)v;
                else
                    ((__bf16*)outp)[((size_t)(b * Hn + h) * 64 + d) * 1024 + s] = (__bf16)v;
            }
        }
    }
}

// ---------------------------------------------------------------------------
// Output GEMM, split-K=2 (round-4 version, unchanged: BK=64, 0 conflicts).
// ---------------------------------------------------------------------------
__global__ __launch_bounds__(256) void gemm_splitk_kernel(
    const __bf16* __restrict__ Xb, const __bf16* __restrict__ WTb,
    const float* __restrict__ bias, float* __restrict__ outp)
{
    __shared__ __align__(16) __bf16 sA[128 * 64];
    __shared__ __align__(16) __bf16 sB[128 * 64];

    const int tid = threadIdx.x;
    const int kz = blockIdx.z;           // 0 or 1: K-half
    const int id = blockIdx.x + (blockIdx.y << 3);
    const int bm = (((id & 7) << 2) | (id >> 6)) * 128;
    const int bn = ((id >> 3) & 7) * 128;

    const int lane = tid & 63;
    const int wave = tid >> 6;
    const int wm = (wave & 1) * 64;
    const int wn = (wave >> 1) * 64;
    const int l15 = lane & 15, quad = lane >> 4;

    floatx4 acc[4][4];
    #pragma unroll
    for (int mi = 0; mi < 4; ++mi)
        #pragma unroll
        for (int ni = 0; ni < 4; ++ni)
            acc[mi][ni] = (floatx4){0.f, 0.f, 0.f, 0.f};

    const int kofs = kz * 512;
    const __bf16* gA[4];
    const __bf16* gB[4];
    #pragma unroll
    for (int j = 0; j < 4; ++j) {
        const int c = j * 256 + tid;
        const int row = c >> 3;
        const int q = (c & 7) ^ (row & 7);
        gA[j] = Xb  + (size_t)(bm + row) * Dm + kofs + q * 8;
        gB[j] = WTb + (size_t)(bn + row) * Dm + kofs + q * 8;
    }
    char* const lA = (char*)sA + (tid & 192) * 16;
    char* const lB = (char*)sB + (tid & 192) * 16;

    for (int kt = 0; kt < 512; kt += 64) {
        #pragma unroll
        for (int j = 0; j < 4; ++j) {
            async_ld16(lA + j * 4096, gA[j] + kt);
            async_ld16(lB + j * 4096, gB[j] + kt);
        }
        __syncthreads();

        #pragma unroll
        for (int ks = 0; ks < 2; ++ks) {
            bf16x8 af[4], bfr[4];
            #pragma unroll
            for (int mi = 0; mi < 4; ++mi) {
                const int r = wm + mi * 16 + l15;
                af[mi] = *(const bf16x8*)(sA + r * 64 + ((((ks << 2) + quad) ^ (r & 7)) * 8));
            }
            #pragma unroll
            for (int ni = 0; ni < 4; ++ni) {
                const int r = wn + ni * 16 + l15;
                bfr[ni] = *(const bf16x8*)(sB + r * 64 + ((((ks << 2) + quad) ^ (r & 7)) * 8));
            }
            #pragma unroll
            for (int mi = 0; mi < 4; ++mi)
                #pragma unroll
                for (int ni = 0; ni < 4; ++ni)
                    acc[mi][ni] = __builtin_amdgcn_mfma_f32_16x16x32_bf16(
                        af[mi], bfr[ni], acc[mi][ni], 0, 0, 0);
        }
        __syncthreads();
    }

    #pragma unroll
    for (int mi = 0; mi < 4; ++mi) {
        #pragma unroll
        for (int ni = 0; ni < 4; ++ni) {
            const int n = bn + wn + ni * 16 + l15;
            const float bv = (kz == 0) ? bias[n] : 0.0f;
            #pragma unroll
            for (int reg = 0; reg < 4; ++reg) {
                const int m = bm + wm + mi * 16 + quad * 4 + reg;
                atomicAdd(outp + (size_t)m * 1024 + n, acc[mi][ni][reg] + bv);
            }
        }
    }
}

// ---------------------------------------------------------------------------
// Flash attention (unchanged)
// ---------------------------------------------------------------------------
__global__ __launch_bounds__(256, 2) void flash_attn_kernel(
    const __bf16* __restrict__ Qh,  // [B,H,S,HD]  (pre-scaled by log2e/32)
    const __bf16* __restrict__ Kh,  // [B,H,S,HD]
    const __bf16* __restrict__ Vt,  // [B,H,HD,S]
    __bf16* __restrict__ ctx)       // [B,S,D]
{
    __shared__ __align__(16) char sKV[2][16384];   // per buf: K 8KB | V^T 8KB
    __shared__ __align__(16) __bf16 sP[4][32 * 64];

    const int tid = threadIdx.x;
    const int wave = tid >> 6, lane = tid & 63;
    const int l15 = lane & 15, quad = lane >> 4;

    // XCD swizzle over 512 blocks
    const int id = blockIdx.x + (blockIdx.y << 3) + (blockIdx.z << 7);
    const int kk = id >> 3;
    const int bh = ((id & 7) << 3) | (kk & 7);
    const int b = bh >> 4, h = bh & 15;
    const int qb = (kk >> 3) * 128 + wave * 32;

    bf16x8 aQ[2][2];
    #pragma unroll
    for (int mi = 0; mi < 2; ++mi)
        #pragma unroll
        for (int ks = 0; ks < 2; ++ks)
            aQ[mi][ks] = *(const bf16x8*)(Qh +
                (size_t)(bh * Sn + qb + mi * 16 + l15) * 64 + ks * 32 + quad * 8);

    const int s0 = tid, s1 = tid + 256;
    const int r0 = s0 >> 3, q0c = (s0 & 7) ^ (r0 & 7);
    const int r1 = s1 >> 3, q1c = (s1 & 7) ^ (r1 & 7);
    const __bf16* gK0 = Kh + (size_t)(bh * Sn + r0) * 64 + q0c * 8;
    const __bf16* gK1 = Kh + (size_t)(bh * Sn + r1) * 64 + q1c * 8;
    const __bf16* gV0 = Vt + (size_t)(bh * 64 + r0) * Sn + q0c * 8;
    const __bf16* gV1 = Vt + (size_t)(bh * 64 + r1) * Sn + q1c * 8;
    const int wofs = (tid & 192) * 16;

    floatx4 oacc[2][4];
    #pragma unroll
    for (int mi = 0; mi < 2; ++mi)
        #pragma unroll
        for (int nf = 0; nf < 4; ++nf)
            oacc[mi][nf] = (floatx4){0.f, 0.f, 0.f, 0.f};
    float lsum[2][4];
    #pragma unroll
    for (int mi = 0; mi < 2; ++mi)
        #pragma unroll
        for (int r = 0; r < 4; ++r) lsum[mi][r] = 0.0f;

    __bf16* sPw = sP[wave];

    {
        char* bK = sKV[0];
        char* bV = sKV[0] + 8192;
        async_ld16(bK + wofs,        gK0);
        async_ld16(bK + 4096 + wofs, gK1);
        async_ld16(bV + wofs,        gV0);
        async_ld16(bV + 4096 + wofs, gV1);
    }

    int cur = 0;
    for (int it = 0; it < 16; ++it) {
        __syncthreads();

        if (it + 1 < 16) {
            const int t0n = (it + 1) * 64;
            char* bK = sKV[cur ^ 1];
            char* bV = sKV[cur ^ 1] + 8192;
            async_ld16(bK + wofs,        gK0 + (size_t)t0n * 64);
            async_ld16(bK + 4096 + wofs, gK1 + (size_t)t0n * 64);
            async_ld16(bV + wofs,        gV0 + t0n);
            async_ld16(bV + 4096 + wofs, gV1 + t0n);
        }

        const __bf16* sK = (const __bf16*)sKV[cur];
        const __bf16* sV = (const __bf16*)(sKV[cur] + 8192);

        floatx4 sc[2][4];
        #pragma unroll
        for (int mi = 0; mi < 2; ++mi)
            #pragma unroll
            for (int nf = 0; nf < 4; ++nf)
                sc[mi][nf] = (floatx4){0.f, 0.f, 0.f, 0.f};
        #pragma unroll
        for (int ks = 0; ks < 2; ++ks) {
            bf16x8 bK[4];
            #pragma unroll
            for (int nf = 0; nf < 4; ++nf) {
                const int n = nf * 16 + l15;
                bK[nf] = *(const bf16x8*)(sK + (n * 8 + (((ks << 2) + quad) ^ (n & 7))) * 8);
            }
            #pragma unroll
            for (int mi = 0; mi < 2; ++mi)
                #pragma unroll
                for (int nf = 0; nf < 4; ++nf)
                    sc[mi][nf] = __builtin_amdgcn_mfma_f32_16x16x32_bf16(
                        aQ[mi][ks], bK[nf], sc[mi][nf], 0, 0, 0);
        }

        #pragma unroll
        for (int mi = 0; mi < 2; ++mi)
            #pragma unroll
            for (int nf = 0; nf < 4; ++nf) {
                const int t = nf * 16 + l15;
                #pragma unroll
                for (int r = 0; r < 4; ++r) {
                    const float p = __builtin_amdgcn_exp2f(fminf(sc[mi][nf][r], 126.0f));
                    const __bf16 pb = (__bf16)p;
                    lsum[mi][r] += (float)pb;
                    const int rr = mi * 16 + quad * 4 + r;
                    sPw[(rr * 8 + ((t >> 3) ^ (rr & 7))) * 8 + (t & 7)] = pb;
                }
            }

        #pragma unroll
        for (int ks = 0; ks < 2; ++ks) {
            bf16x8 aP[2], bV[4];
            #pragma unroll
            for (int mi = 0; mi < 2; ++mi) {
                const int r = mi * 16 + l15;
                aP[mi] = *(const bf16x8*)(sPw + (r * 8 + (((ks << 2) + quad) ^ (r & 7))) * 8);
            }
            #pragma unroll
            for (int nf = 0; nf < 4; ++nf) {
                const int n = nf * 16 + l15;
                bV[nf] = *(const bf16x8*)(sV + (n * 8 + (((ks << 2) + quad) ^ (n & 7))) * 8);
            }
            #pragma unroll
            for (int mi = 0; mi < 2; ++mi)
                #pragma unroll
                for (int nf = 0; nf < 4; ++nf)
                    oacc[mi][nf] = __builtin_amdgcn_mfma_f32_16x16x32_bf16(
                        aP[mi], bV[nf], oacc[mi][nf], 0, 0, 0);
        }

        cur ^= 1;
    }

    float linv[2][4];
    #pragma unroll
    for (int mi = 0; mi < 2; ++mi)
        #pragma unroll
        for (int r = 0; r < 4; ++r) {
            float l = lsum[mi][r];
            l += __shfl_xor(l, 1, 64);
            l += __shfl_xor(l, 2, 64);
            l += __shfl_xor(l, 4, 64);
            l += __shfl_xor(l, 8, 64);
            linv[mi][r] = 1.0f / l;
        }

    #pragma unroll
    for (int mi = 0; mi < 2; ++mi)
        #pragma unroll
        for (int nf = 0; nf < 4; ++nf) {
            const int d = h * 64 + nf * 16 + l15;
            #pragma unroll
            for (int reg = 0; reg < 4; ++reg) {
                const int s = qb + mi * 16 + quad * 4 + reg;
                ctx[(size_t)(b * Sn + s) * Dm + d] =
                    (__bf16)(oacc[mi][nf][reg] * linv[mi][reg]);
            }
        }
}

// ---------------------------------------------------------------------------
extern "C" void kernel_launch(void* const* d_in, const int* in_sizes, int n_in,
                              void* d_out, int out_size, void* d_ws, size_t ws_size,
                              hipStream_t stream)
{
    const float* q  = (const float*)d_in[0];
    const float* k  = (const float*)d_in[1];
    const float* v  = (const float*)d_in[2];
    const float* Wq = (const float*)d_in[3];
    const float* bq = (const float*)d_in[4];
    const float* Wk = (const float*)d_in[5];
    const float* bk = (const float*)d_in[6];
    const float* Wv = (const float*)d_in[7];
    const float* bv = (const float*)d_in[8];
    const float* Wo = (const float*)d_in[9];
    const float* bo = (const float*)d_in[10];

    char* ws = (char*)d_ws;
    const size_t MB = 1024 * 1024;
    __bf16* qb_ = (__bf16*)(ws);            // 8 MB [4096][1024]
    __bf16* kb_ = (__bf16*)(ws + 8 * MB);
    __bf16* vb_ = (__bf16*)(ws + 16 * MB);
    __bf16* WTq = (__bf16*)(ws + 24 * MB);  // 2 MB each [N][K]
    __bf16* WTk = (__bf16*)(ws + 26 * MB);
    __bf16* WTv = (__bf16*)(ws + 28 * MB);
    __bf16* WTo = (__bf16*)(ws + 30 * MB);
    __bf16* Qh  = (__bf16*)(ws + 32 * MB);  // 8 MB [B,H,S,HD] (pre-scaled)
    __bf16* Kh  = (__bf16*)(ws + 40 * MB);  // 8 MB [B,H,S,HD]
    __bf16* Vt  = (__bf16*)(ws + 48 * MB);  // 8 MB [B,H,HD,S]
    __bf16* ctx = (__bf16*)(ws + 56 * MB);  // 8 MB [B,S,D]

    PrepArgs pa;
    pa.qkv[0] = q; pa.qkv[1] = k; pa.qkv[2] = v;
    pa.qkv_o[0] = qb_; pa.qkv_o[1] = kb_; pa.qkv_o[2] = vb_;
    pa.W[0] = Wq; pa.W[1] = Wk; pa.W[2] = Wv; pa.W[3] = Wo;
    pa.WT[0] = WTq; pa.WT[1] = WTk; pa.WT[2] = WTv; pa.WT[3] = WTo;
    pa.out_zero = (float*)d_out;
    prep_kernel<<<dim3(2048, 1, 8), 256, 0, stream>>>(pa);

    const float QSCALE = 0.0450842200f;  // log2(e) / 32

    GemmArgs qkv;
    qkv.X[0] = qb_;  qkv.X[1] = kb_;  qkv.X[2] = vb_;
    qkv.WT[0] = WTq; qkv.WT[1] = WTk; qkv.WT[2] = WTv;
    qkv.bias[0] = bq; qkv.bias[1] = bk; qkv.bias[2] = bv;
    qkv.out[0] = Qh;  qkv.out[1] = Kh;  qkv.out[2] = Vt;
    qkv.layout[0] = 0; qkv.layout[1] = 0; qkv.layout[2] = 1;
    qkv.esc[0] = QSCALE; qkv.esc[1] = 1.0f; qkv.esc[2] = 1.0f;
    gemm_qkv_8ph<<<dim3(192, 1, 1), 512, 0, stream>>>(qkv);

    flash_attn_kernel<<<dim3(8, 16, 4), 256, 0, stream>>>(Qh, Kh, Vt, ctx);

    gemm_splitk_kernel<<<dim3(8, 32, 2), 256, 0, stream>>>(
        ctx, WTo, bo, (float*)d_out);
}

// Round 6
// 213.733 us; speedup vs baseline: 1.1694x; 1.1694x over previous
//
#include <hip/hip_runtime.h>
#include <math.h>

#define Dm 1024
#define Hn 16
#define HDn 64
#define Sn 1024

typedef __attribute__((ext_vector_type(8))) __bf16 bf16x8;
typedef __attribute__((ext_vector_type(4))) float floatx4;

__device__ __forceinline__ void async_ld16(void* lds, const void* g) {
    __builtin_amdgcn_global_load_lds(
        (const __attribute__((address_space(1))) void*)g,
        (__attribute__((address_space(3))) void*)lds,
        16, 0, 0);
}

// ---------------------------------------------------------------------------
// Prep kernel. grid (2048, 1, 7), 256 thr.  (round-4 minus the d_out zero
// slice -- no longer needed, the reduce kernel writes every element)
//  z 0..2 : fp32->bf16 cast of q/k/v (x < 2048, 8 elems/thread)
//  z 3..6 : W [k][n] fp32 -> WT [n][k] bf16, 64x64 tiles (x < 256)
// ---------------------------------------------------------------------------
struct PrepArgs {
    const float* qkv[3];
    __bf16*      qkv_o[3];
    const float* W[4];
    __bf16*      WT[4];
};

__global__ __launch_bounds__(256) void prep_kernel(PrepArgs a)
{
    __shared__ float sT[64][65];
    const int z = blockIdx.z, x = blockIdx.x, tid = threadIdx.x;

    if (z < 3) {
        const float* src = a.qkv[z];
        __bf16* dst = a.qkv_o[z];
        const int lin = x * 256 + tid;
        const float4 v0 = ((const float4*)src)[lin * 2];
        const float4 v1 = ((const float4*)src)[lin * 2 + 1];
        bf16x8 o;
        o[0] = (__bf16)v0.x; o[1] = (__bf16)v0.y; o[2] = (__bf16)v0.z; o[3] = (__bf16)v0.w;
        o[4] = (__bf16)v1.x; o[5] = (__bf16)v1.y; o[6] = (__bf16)v1.z; o[7] = (__bf16)v1.w;
        ((bf16x8*)dst)[lin] = o;
    } else {
        if (x >= 256) return;
        const float* W = a.W[z - 3];
        __bf16* O = a.WT[z - 3];
        const int bi = (x >> 4) * 64, bj = (x & 15) * 64;
        const int colr = tid & 63, rowg = tid >> 6;
        #pragma unroll
        for (int i = 0; i < 16; ++i) {
            const int kk = i * 4 + rowg;
            sT[kk][colr] = W[(size_t)(bi + kk) * Dm + bj + colr];
        }
        __syncthreads();
        #pragma unroll
        for (int i = 0; i < 16; ++i) {
            const int rn = i * 4 + rowg;
            O[(size_t)(bj + rn) * Dm + bi + colr] = (__bf16)sT[colr][rn];
        }
    }
}

// ---------------------------------------------------------------------------
// QKV GEMM: round-4 version EXACTLY (m97 BK=32 schedule + conflict-free
// paired-row XOR swizzle; measured 44.2us, SQ_LDS_BANK_CONFLICT = 0).
// ---------------------------------------------------------------------------
struct GemmArgs {
    const __bf16* X[3];
    const __bf16* WT[3];
    const float*  bias[3];
    void*         out[3];
    int   layout[3];
    float esc[3];
};

__global__ __launch_bounds__(256) void gemm_bf16_kernel(GemmArgs args)
{
    __shared__ __align__(16) __bf16 sA[128 * 32];
    __shared__ __align__(16) __bf16 sB[128 * 32];

    const int z = blockIdx.z;
    const __bf16* __restrict__ Xb  = args.X[z];
    const __bf16* __restrict__ WTb = args.WT[z];
    const float*  __restrict__ bias = args.bias[z];
    void* __restrict__ outp = args.out[z];
    const int layout = args.layout[z];
    const float escale = args.esc[z];

    const int tid = threadIdx.x;
    const int id = blockIdx.x + (blockIdx.y << 3);
    const int bm = (((id & 7) << 2) | (id >> 6)) * 128;
    const int bn = ((id >> 3) & 7) * 128;

    const int lane = tid & 63;
    const int wave = tid >> 6;
    const int wm = (wave & 1) * 64;
    const int wn = (wave >> 1) * 64;
    const int l15 = lane & 15, quad = lane >> 4;

    floatx4 acc[4][4];
    #pragma unroll
    for (int mi = 0; mi < 4; ++mi)
        #pragma unroll
        for (int ni = 0; ni < 4; ++ni)
            acc[mi][ni] = (floatx4){0.f, 0.f, 0.f, 0.f};

    const int cA0 = tid,       p0 = cA0 >> 3, g0 = (cA0 & 7) ^ (p0 & 7);
    const int cA1 = tid + 256, p1 = cA1 >> 3, g1 = (cA1 & 7) ^ (p1 & 7);
    const int r0 = 2 * p0 + (g0 >> 2), q0 = g0 & 3;
    const int r1 = 2 * p1 + (g1 >> 2), q1 = g1 & 3;
    const __bf16* gA0 = Xb  + (size_t)(bm + r0) * Dm + q0 * 8;
    const __bf16* gA1 = Xb  + (size_t)(bm + r1) * Dm + q1 * 8;
    const __bf16* gB0 = WTb + (size_t)(bn + r0) * Dm + q0 * 8;
    const __bf16* gB1 = WTb + (size_t)(bn + r1) * Dm + q1 * 8;
    char* const lA0 = (char*)sA + (tid & 192) * 16;
    char* const lA1 = (char*)sA + (256 + (tid & 192)) * 16;
    char* const lB0 = (char*)sB + (tid & 192) * 16;
    char* const lB1 = (char*)sB + (256 + (tid & 192)) * 16;

    int offA[4], offB[4];
    #pragma unroll
    for (int mi = 0; mi < 4; ++mi) {
        const int r = wm + mi * 16 + l15;
        const int p = r >> 1;
        const int cc = ((((r & 1) << 2) | quad)) ^ (p & 7);
        offA[mi] = p * 64 + cc * 8;
    }
    #pragma unroll
    for (int ni = 0; ni < 4; ++ni) {
        const int r = wn + ni * 16 + l15;
        const int p = r >> 1;
        const int cc = ((((r & 1) << 2) | quad)) ^ (p & 7);
        offB[ni] = p * 64 + cc * 8;
    }

    for (int kt = 0; kt < Dm; kt += 32) {
        async_ld16(lA0, gA0 + kt);
        async_ld16(lA1, gA1 + kt);
        async_ld16(lB0, gB0 + kt);
        async_ld16(lB1, gB1 + kt);
        __syncthreads();

        bf16x8 af[4], bfr[4];
        #pragma unroll
        for (int mi = 0; mi < 4; ++mi) af[mi] = *(const bf16x8*)(sA + offA[mi]);
        #pragma unroll
        for (int ni = 0; ni < 4; ++ni) bfr[ni] = *(const bf16x8*)(sB + offB[ni]);
        #pragma unroll
        for (int mi = 0; mi < 4; ++mi)
            #pragma unroll
            for (int ni = 0; ni < 4; ++ni)
                acc[mi][ni] = __builtin_amdgcn_mfma_f32_16x16x32_bf16(
                    af[mi], bfr[ni], acc[mi][ni], 0, 0, 0);
        __syncthreads();
    }

    #pragma unroll
    for (int mi = 0; mi < 4; ++mi) {
        #pragma unroll
        for (int ni = 0; ni < 4; ++ni) {
            const int n = bn + wn + ni * 16 + l15;
            const float bv = bias[n];
            const int h = n >> 6, d = n & 63;
            #pragma unroll
            for (int reg = 0; reg < 4; ++reg) {
                const int m = bm + wm + mi * 16 + quad * 4 + reg;
                const int b = m >> 10, s = m & 1023;
                float v = fmaxf(acc[mi][ni][reg] + bv, 0.0f) * escale;
                if (layout == 0)
                    ((__bf16*)outp)[((size_t)(b * Hn + h) * 1024 + s) * 64 + d] = (__bf16)v;
                else
                    ((__bf16*)outp)[((size_t)(b * Hn + h) * 64 + d) * 1024 + s] = (__bf16)v;
            }
        }
    }
}

// ---------------------------------------------------------------------------
// Output GEMM, split-K=2: GEMM body unchanged (round-2/4 BK=64, 0 conflicts).
// NEW epilogue: plain fp32 stores of the K-half partial into P0 (kz==0, with
// bias) or P1 (kz==1) -- no atomics, no pre-zeroed d_out. Deterministic sum
// happens in reduce_kernel. P0/P1 overlay workspace that is dead by the time
// this kernel runs (qb_/kb_ and Qh/Kh respectively).
// ---------------------------------------------------------------------------
__global__ __launch_bounds__(256) void gemm_splitk_kernel(
    const __bf16* __restrict__ Xb, const __bf16* __restrict__ WTb,
    const float* __restrict__ bias, float* __restrict__ P0,
    float* __restrict__ P1)
{
    __shared__ __align__(16) __bf16 sA[128 * 64];
    __shared__ __align__(16) __bf16 sB[128 * 64];

    const int tid = threadIdx.x;
    const int kz = blockIdx.z;           // 0 or 1: K-half
    const int id = blockIdx.x + (blockIdx.y << 3);
    const int bm = (((id & 7) << 2) | (id >> 6)) * 128;
    const int bn = ((id >> 3) & 7) * 128;

    const int lane = tid & 63;
    const int wave = tid >> 6;
    const int wm = (wave & 1) * 64;
    const int wn = (wave >> 1) * 64;
    const int l15 = lane & 15, quad = lane >> 4;

    floatx4 acc[4][4];
    #pragma unroll
    for (int mi = 0; mi < 4; ++mi)
        #pragma unroll
        for (int ni = 0; ni < 4; ++ni)
            acc[mi][ni] = (floatx4){0.f, 0.f, 0.f, 0.f};

    const int kofs = kz * 512;
    const __bf16* gA[4];
    const __bf16* gB[4];
    #pragma unroll
    for (int j = 0; j < 4; ++j) {
        const int c = j * 256 + tid;
        const int row = c >> 3;
        const int q = (c & 7) ^ (row & 7);
        gA[j] = Xb  + (size_t)(bm + row) * Dm + kofs + q * 8;
        gB[j] = WTb + (size_t)(bn + row) * Dm + kofs + q * 8;
    }
    char* const lA = (char*)sA + (tid & 192) * 16;
    char* const lB = (char*)sB + (tid & 192) * 16;

    for (int kt = 0; kt < 512; kt += 64) {
        #pragma unroll
        for (int j = 0; j < 4; ++j) {
            async_ld16(lA + j * 4096, gA[j] + kt);
            async_ld16(lB + j * 4096, gB[j] + kt);
        }
        __syncthreads();

        #pragma unroll
        for (int ks = 0; ks < 2; ++ks) {
            bf16x8 af[4], bfr[4];
            #pragma unroll
            for (int mi = 0; mi < 4; ++mi) {
                const int r = wm + mi * 16 + l15;
                af[mi] = *(const bf16x8*)(sA + r * 64 + ((((ks << 2) + quad) ^ (r & 7)) * 8));
            }
            #pragma unroll
            for (int ni = 0; ni < 4; ++ni) {
                const int r = wn + ni * 16 + l15;
                bfr[ni] = *(const bf16x8*)(sB + r * 64 + ((((ks << 2) + quad) ^ (r & 7)) * 8));
            }
            #pragma unroll
            for (int mi = 0; mi < 4; ++mi)
                #pragma unroll
                for (int ni = 0; ni < 4; ++ni)
                    acc[mi][ni] = __builtin_amdgcn_mfma_f32_16x16x32_bf16(
                        af[mi], bfr[ni], acc[mi][ni], 0, 0, 0);
        }
        __syncthreads();
    }

    float* __restrict__ P = (kz == 0) ? P0 : P1;
    #pragma unroll
    for (int mi = 0; mi < 4; ++mi) {
        #pragma unroll
        for (int ni = 0; ni < 4; ++ni) {
            const int n = bn + wn + ni * 16 + l15;
            const float bv = (kz == 0) ? bias[n] : 0.0f;
            #pragma unroll
            for (int reg = 0; reg < 4; ++reg) {
                const int m = bm + wm + mi * 16 + quad * 4 + reg;
                P[(size_t)m * 1024 + n] = acc[mi][ni][reg] + bv;
            }
        }
    }
}

// ---------------------------------------------------------------------------
// Reduce: d_out = P0 + P1. 4M floats, 2048 blocks x 256 thr x 8 floats.
// ---------------------------------------------------------------------------
__global__ __launch_bounds__(256) void reduce_kernel(
    const float* __restrict__ P0, const float* __restrict__ P1,
    float* __restrict__ outp)
{
    const int i = (blockIdx.x * 256 + threadIdx.x) * 2;
    const float4 a0 = ((const float4*)P0)[i];
    const float4 a1 = ((const float4*)P0)[i + 1];
    const float4 b0 = ((const float4*)P1)[i];
    const float4 b1 = ((const float4*)P1)[i + 1];
    float4 o0, o1;
    o0.x = a0.x + b0.x; o0.y = a0.y + b0.y; o0.z = a0.z + b0.z; o0.w = a0.w + b0.w;
    o1.x = a1.x + b1.x; o1.y = a1.y + b1.y; o1.z = a1.z + b1.z; o1.w = a1.w + b1.w;
    ((float4*)outp)[i]     = o0;
    ((float4*)outp)[i + 1] = o1;
}

// ---------------------------------------------------------------------------
// Flash attention (unchanged from round-4)
// ---------------------------------------------------------------------------
__global__ __launch_bounds__(256, 2) void flash_attn_kernel(
    const __bf16* __restrict__ Qh,  // [B,H,S,HD]  (pre-scaled by log2e/32)
    const __bf16* __restrict__ Kh,  // [B,H,S,HD]
    const __bf16* __restrict__ Vt,  // [B,H,HD,S]
    __bf16* __restrict__ ctx)       // [B,S,D]
{
    __shared__ __align__(16) char sKV[2][16384];   // per buf: K 8KB | V^T 8KB
    __shared__ __align__(16) __bf16 sP[4][32 * 64];

    const int tid = threadIdx.x;
    const int wave = tid >> 6, lane = tid & 63;
    const int l15 = lane & 15, quad = lane >> 4;

    // XCD swizzle over 512 blocks
    const int id = blockIdx.x + (blockIdx.y << 3) + (blockIdx.z << 7);
    const int kk = id >> 3;
    const int bh = ((id & 7) << 3) | (kk & 7);
    const int b = bh >> 4, h = bh & 15;
    const int qb = (kk >> 3) * 128 + wave * 32;

    bf16x8 aQ[2][2];
    #pragma unroll
    for (int mi = 0; mi < 2; ++mi)
        #pragma unroll
        for (int ks = 0; ks < 2; ++ks)
            aQ[mi][ks] = *(const bf16x8*)(Qh +
                (size_t)(bh * Sn + qb + mi * 16 + l15) * 64 + ks * 32 + quad * 8);

    const int s0 = tid, s1 = tid + 256;
    const int r0 = s0 >> 3, q0c = (s0 & 7) ^ (r0 & 7);
    const int r1 = s1 >> 3, q1c = (s1 & 7) ^ (r1 & 7);
    const __bf16* gK0 = Kh + (size_t)(bh * Sn + r0) * 64 + q0c * 8;
    const __bf16* gK1 = Kh + (size_t)(bh * Sn + r1) * 64 + q1c * 8;
    const __bf16* gV0 = Vt + (size_t)(bh * 64 + r0) * Sn + q0c * 8;
    const __bf16* gV1 = Vt + (size_t)(bh * 64 + r1) * Sn + q1c * 8;
    const int wofs = (tid & 192) * 16;

    floatx4 oacc[2][4];
    #pragma unroll
    for (int mi = 0; mi < 2; ++mi)
        #pragma unroll
        for (int nf = 0; nf < 4; ++nf)
            oacc[mi][nf] = (floatx4){0.f, 0.f, 0.f, 0.f};
    float lsum[2][4];
    #pragma unroll
    for (int mi = 0; mi < 2; ++mi)
        #pragma unroll
        for (int r = 0; r < 4; ++r) lsum[mi][r] = 0.0f;

    __bf16* sPw = sP[wave];

    {
        char* bK = sKV[0];
        char* bV = sKV[0] + 8192;
        async_ld16(bK + wofs,        gK0);
        async_ld16(bK + 4096 + wofs, gK1);
        async_ld16(bV + wofs,        gV0);
        async_ld16(bV + 4096 + wofs, gV1);
    }

    int cur = 0;
    for (int it = 0; it < 16; ++it) {
        __syncthreads();

        if (it + 1 < 16) {
            const int t0n = (it + 1) * 64;
            char* bK = sKV[cur ^ 1];
            char* bV = sKV[cur ^ 1] + 8192;
            async_ld16(bK + wofs,        gK0 + (size_t)t0n * 64);
            async_ld16(bK + 4096 + wofs, gK1 + (size_t)t0n * 64);
            async_ld16(bV + wofs,        gV0 + t0n);
            async_ld16(bV + 4096 + wofs, gV1 + t0n);
        }

        const __bf16* sK = (const __bf16*)sKV[cur];
        const __bf16* sV = (const __bf16*)(sKV[cur] + 8192);

        floatx4 sc[2][4];
        #pragma unroll
        for (int mi = 0; mi < 2; ++mi)
            #pragma unroll
            for (int nf = 0; nf < 4; ++nf)
                sc[mi][nf] = (floatx4){0.f, 0.f, 0.f, 0.f};
        #pragma unroll
        for (int ks = 0; ks < 2; ++ks) {
            bf16x8 bK[4];
            #pragma unroll
            for (int nf = 0; nf < 4; ++nf) {
                const int n = nf * 16 + l15;
                bK[nf] = *(const bf16x8*)(sK + (n * 8 + (((ks << 2) + quad) ^ (n & 7))) * 8);
            }
            #pragma unroll
            for (int mi = 0; mi < 2; ++mi)
                #pragma unroll
                for (int nf = 0; nf < 4; ++nf)
                    sc[mi][nf] = __builtin_amdgcn_mfma_f32_16x16x32_bf16(
                        aQ[mi][ks], bK[nf], sc[mi][nf], 0, 0, 0);
        }

        #pragma unroll
        for (int mi = 0; mi < 2; ++mi)
            #pragma unroll
            for (int nf = 0; nf < 4; ++nf) {
                const int t = nf * 16 + l15;
                #pragma unroll
                for (int r = 0; r < 4; ++r) {
                    const float p = __builtin_amdgcn_exp2f(fminf(sc[mi][nf][r], 126.0f));
                    const __bf16 pb = (__bf16)p;
                    lsum[mi][r] += (float)pb;
                    const int rr = mi * 16 + quad * 4 + r;
                    sPw[(rr * 8 + ((t >> 3) ^ (rr & 7))) * 8 + (t & 7)] = pb;
                }
            }

        #pragma unroll
        for (int ks = 0; ks < 2; ++ks) {
            bf16x8 aP[2], bV[4];
            #pragma unroll
            for (int mi = 0; mi < 2; ++mi) {
                const int r = mi * 16 + l15;
                aP[mi] = *(const bf16x8*)(sPw + (r * 8 + (((ks << 2) + quad) ^ (r & 7))) * 8);
            }
            #pragma unroll
            for (int nf = 0; nf < 4; ++nf) {
                const int n = nf * 16 + l15;
                bV[nf] = *(const bf16x8*)(sV + (n * 8 + (((ks << 2) + quad) ^ (n & 7))) * 8);
            }
            #pragma unroll
            for (int mi = 0; mi < 2; ++mi)
                #pragma unroll
                for (int nf = 0; nf < 4; ++nf)
                    oacc[mi][nf] = __builtin_amdgcn_mfma_f32_16x16x32_bf16(
                        aP[mi], bV[nf], oacc[mi][nf], 0, 0, 0);
        }

        cur ^= 1;
    }

    float linv[2][4];
    #pragma unroll
    for (int mi = 0; mi < 2; ++mi)
        #pragma unroll
        for (int r = 0; r < 4; ++r) {
            float l = lsum[mi][r];
            l += __shfl_xor(l, 1, 64);
            l += __shfl_xor(l, 2, 64);
            l += __shfl_xor(l, 4, 64);
            l += __shfl_xor(l, 8, 64);
            linv[mi][r] = 1.0f / l;
        }

    #pragma unroll
    for (int mi = 0; mi < 2; ++mi)
        #pragma unroll
        for (int nf = 0; nf < 4; ++nf) {
            const int d = h * 64 + nf * 16 + l15;
            #pragma unroll
            for (int reg = 0; reg < 4; ++reg) {
                const int s = qb + mi * 16 + quad * 4 + reg;
                ctx[(size_t)(b * Sn + s) * Dm + d] =
                    (__bf16)(oacc[mi][nf][reg] * linv[mi][reg]);
            }
        }
}

// ---------------------------------------------------------------------------
extern "C" void kernel_launch(void* const* d_in, const int* in_sizes, int n_in,
                              void* d_out, int out_size, void* d_ws, size_t ws_size,
                              hipStream_t stream)
{
    const float* q  = (const float*)d_in[0];
    const float* k  = (const float*)d_in[1];
    const float* v  = (const float*)d_in[2];
    const float* Wq = (const float*)d_in[3];
    const float* bq = (const float*)d_in[4];
    const float* Wk = (const float*)d_in[5];
    const float* bk = (const float*)d_in[6];
    const float* Wv = (const float*)d_in[7];
    const float* bv = (const float*)d_in[8];
    const float* Wo = (const float*)d_in[9];
    const float* bo = (const float*)d_in[10];

    char* ws = (char*)d_ws;
    const size_t MB = 1024 * 1024;
    __bf16* qb_ = (__bf16*)(ws);            // 8 MB [4096][1024]
    __bf16* kb_ = (__bf16*)(ws + 8 * MB);
    __bf16* vb_ = (__bf16*)(ws + 16 * MB);
    __bf16* WTq = (__bf16*)(ws + 24 * MB);  // 2 MB each [N][K]
    __bf16* WTk = (__bf16*)(ws + 26 * MB);
    __bf16* WTv = (__bf16*)(ws + 28 * MB);
    __bf16* WTo = (__bf16*)(ws + 30 * MB);
    __bf16* Qh  = (__bf16*)(ws + 32 * MB);  // 8 MB [B,H,S,HD] (pre-scaled)
    __bf16* Kh  = (__bf16*)(ws + 40 * MB);  // 8 MB [B,H,S,HD]
    __bf16* Vt  = (__bf16*)(ws + 48 * MB);  // 8 MB [B,H,HD,S]
    __bf16* ctx = (__bf16*)(ws + 56 * MB);  // 8 MB [B,S,D]
    // split-K partials (16 MB fp32 each), overlaying DEAD buffers:
    // P0 over qb_/kb_ (dead after qkv gemm), P1 over Qh/Kh (dead after attn).
    float* P0 = (float*)(ws);
    float* P1 = (float*)(ws + 32 * MB);

    PrepArgs pa;
    pa.qkv[0] = q; pa.qkv[1] = k; pa.qkv[2] = v;
    pa.qkv_o[0] = qb_; pa.qkv_o[1] = kb_; pa.qkv_o[2] = vb_;
    pa.W[0] = Wq; pa.W[1] = Wk; pa.W[2] = Wv; pa.W[3] = Wo;
    pa.WT[0] = WTq; pa.WT[1] = WTk; pa.WT[2] = WTv; pa.WT[3] = WTo;
    prep_kernel<<<dim3(2048, 1, 7), 256, 0, stream>>>(pa);

    const float QSCALE = 0.0450842200f;  // log2(e) / 32

    GemmArgs qkv;
    qkv.X[0] = qb_;  qkv.X[1] = kb_;  qkv.X[2] = vb_;
    qkv.WT[0] = WTq; qkv.WT[1] = WTk; qkv.WT[2] = WTv;
    qkv.bias[0] = bq; qkv.bias[1] = bk; qkv.bias[2] = bv;
    qkv.out[0] = Qh;  qkv.out[1] = Kh;  qkv.out[2] = Vt;
    qkv.layout[0] = 0; qkv.layout[1] = 0; qkv.layout[2] = 1;
    qkv.esc[0] = QSCALE; qkv.esc[1] = 1.0f; qkv.esc[2] = 1.0f;
    gemm_bf16_kernel<<<dim3(8, 32, 3), 256, 0, stream>>>(qkv);

    flash_attn_kernel<<<dim3(8, 16, 4), 256, 0, stream>>>(Qh, Kh, Vt, ctx);

    gemm_splitk_kernel<<<dim3(8, 32, 2), 256, 0, stream>>>(
        ctx, WTo, bo, P0, P1);

    reduce_kernel<<<dim3(2048, 1, 1), 256, 0, stream>>>(P0, P1, (float*)d_out);
}